// Round 4
// baseline (239.596 us; speedup 1.0000x reference)
//
#include <hip/hip_runtime.h>
#include <hip/hip_bf16.h>

#define D_MODEL 1024
#define NH 16
#define DKH 64
#define BB 2
#define SS 2048
#define MTOT (BB * SS)  // 4096

typedef __hip_bfloat16 bf16;
typedef __attribute__((ext_vector_type(8))) short short8;
typedef __attribute__((ext_vector_type(4))) short short4v;
typedef __attribute__((ext_vector_type(4))) float floatx4;

__device__ __forceinline__ bf16 f2bf(float x) { return __float2bfloat16(x); }

// async global->LDS, 16B per lane; LDS dest must be wave-uniform (HW adds lane*16)
__device__ __forceinline__ void async_cp16(const void* g, void* l) {
  __builtin_amdgcn_global_load_lds(
      (const __attribute__((address_space(1))) unsigned int*)g,
      (__attribute__((address_space(3))) unsigned int*)l, 16, 0, 0);
}

// ---------------------------------------------------------------------------
// Pre-conversion fp32 -> bf16: 4 weight matrices (4 x 1M elems) AND the three
// input activations (3 x 4M elems). Removes all fp32 handling from the GEMMs.
// Converted q/k live in d_out (16 MB, not written until out-proj,
// stream-ordered); v lives in ws.
// ---------------------------------------------------------------------------
__global__ __launch_bounds__(256) void convert_kernel(
    const float* __restrict__ wq, const float* __restrict__ wk,
    const float* __restrict__ wv, const float* __restrict__ wo,
    const float* __restrict__ qi, const float* __restrict__ ki,
    const float* __restrict__ vi, bf16* __restrict__ Wb,
    bf16* __restrict__ Qi, bf16* __restrict__ Ki, bf16* __restrict__ Vi) {
  const int id = blockIdx.x * 256 + threadIdx.x;  // float4 index, 0..4M-1
  const float* src;
  bf16* dst;
  if (id < (1 << 20)) {  // weights: 4 x 256K float4
    const int m = id >> 18, loc = id & 0x3FFFF;
    src = ((m == 0) ? wq : (m == 1) ? wk : (m == 2) ? wv : wo) + (size_t)loc * 4;
    dst = Wb + ((size_t)m << 20) + (size_t)loc * 4;
  } else {  // inputs: 3 x 1M float4
    const int t = id - (1 << 20);
    const int m = t >> 20, loc = t & 0xFFFFF;
    src = ((m == 0) ? qi : (m == 1) ? ki : vi) + (size_t)loc * 4;
    dst = ((m == 0) ? Qi : (m == 1) ? Ki : Vi) + (size_t)loc * 4;
  }
  const float4 v = *(const float4*)src;
  short4v s;
  bf16* pb = (bf16*)&s;
  pb[0] = f2bf(v.x); pb[1] = f2bf(v.y); pb[2] = f2bf(v.z); pb[3] = f2bf(v.w);
  *(short4v*)dst = s;
}

// ---------------------------------------------------------------------------
// QKV GEMM r13: 256x256 tile, 512 threads (8 waves, 2Mx4N), BK=32, 3-buffer
// cyclic pipeline with COUNTED vmcnt (T3+T4): the 2-phase drain-to-0 barrier
// was the bottleneck (MfmaUtil 23%, conflicts 0, HBM 19% -> schedule-bound).
// Per iter: vmcnt(4) drains ONLY buf t%3's 4 global_load_lds (next tile's 4
// stay in flight) -> raw s_barrier (NOT __syncthreads: that emits vmcnt(0))
// -> issue prefetch into buf (t+2)%3 -> 12x ds_read_b128 -> 32 MFMA under
// setprio(1) (T5 pays on phase-split schedules, m218b).
// Buffer-reuse safety: writes into (t+2)%3 happen after barrier t; last
// readers of that buf (iter t-1) finished LDS reads (lgkmcnt before MFMA)
// before reaching barrier t. vmcnt ledger: prologue 8 outstanding; steady
// drain4/issue4; last issue t=29; t<31 vmcnt(4), t=31 vmcnt(0).
// LDS = 3 x (16K A + 16K B) = 96 KB -> 1 block/CU, 8 waves/CU. Grid 192.
// r11 granule swizzle carried (proven 0-conflict): source col pre-swizzled
// g ^ ((r>>1)&3), reads XOR same key, LDS linear.
// mode: z<2 -> bf16 row-major C; z==2 -> bf16 V^T layout [n][m].
// ---------------------------------------------------------------------------
__global__ __launch_bounds__(512, 2) void gemm_qkv_kernel(
    const bf16* __restrict__ Qi, const bf16* __restrict__ Ki,
    const bf16* __restrict__ Vi, const bf16* __restrict__ Wb,
    const float* __restrict__ bq, const float* __restrict__ bk,
    const float* __restrict__ bv, bf16* __restrict__ Qw,
    bf16* __restrict__ Kw, bf16* __restrict__ VTw) {
  constexpr int N = 1024, K = 1024, NT = K / 32;
  __shared__ bf16 As[3][256 * 32];  // 48 KB
  __shared__ bf16 Ws[3][256 * 32];  // 48 KB

  const int z = blockIdx.z;
  const bf16* A = (z == 0) ? Qi : (z == 1) ? Ki : Vi;
  const bf16* W = Wb + ((size_t)z << 20);
  const float* Bi = (z == 0) ? bq : (z == 1) ? bk : bv;

  const int tid = threadIdx.x;
  const int wid = tid >> 6, lane = tid & 63, quad = lane >> 4, n16 = lane & 15;
  const int wr = wid >> 2, wc = wid & 3;  // wave grid 2M x 4N; wave out 128x64
  const int bx = blockIdx.x;
  const int bm = bx & 15, bn = bx >> 4;  // bm-fastest (A-panel XCD locality)

  const int rb = lane >> 2, cb = lane & 3;     // 16 rows x 4 chunks(16B)/issue
  const int gsw = (cb ^ ((rb >> 1) & 3)) * 8;  // pre-swizzled source col
  const int rkey = ((n16 >> 1) & 3) * 8;       // read-side granule XOR

  const bf16* Ag0 = A + (size_t)(bm * 256) * K;
  const bf16* Wg0 = W + (size_t)(bn * 256) * K;

  // wave wid stages rows [wid*32, wid*32+32) of both tiles: 4 cp16/thread
  auto issue = [&](int buf, int k0) {
#pragma unroll
    for (int ii = 0; ii < 2; ii++) {
      const int R = wid * 32 + ii * 16 + rb;
      async_cp16(Ag0 + (size_t)R * K + k0 + gsw,
                 (void*)&As[buf][(wid * 32 + ii * 16) * 32]);
      async_cp16(Wg0 + (size_t)R * K + k0 + gsw,
                 (void*)&Ws[buf][(wid * 32 + ii * 16) * 32]);
    }
  };

  floatx4 acc[8][4] = {};
  issue(0, 0);
  issue(1, 32);
  int cur = 0;
  for (int t = 0; t < NT; t++) {
    if (t < NT - 1) {
      asm volatile("s_waitcnt vmcnt(4)" ::: "memory");  // drain cur buf only
    } else {
      asm volatile("s_waitcnt vmcnt(0)" ::: "memory");  // final drain
    }
    __builtin_amdgcn_s_barrier();        // raw: no implicit vmcnt(0)
    __builtin_amdgcn_sched_barrier(0);   // pin reads below the barrier

    if (t < NT - 2) {  // prefetch 2 tiles ahead into the buf being freed
      int nb = cur + 2;
      if (nb >= 3) nb -= 3;
      issue(nb, (t + 2) * 32);
    }

    short8 af[8], bfr[4];
#pragma unroll
    for (int i = 0; i < 8; i++)
      af[i] = *(const short8*)(&As[cur][(wr * 128 + i * 16 + n16) * 32 + ((quad * 8) ^ rkey)]);
#pragma unroll
    for (int j = 0; j < 4; j++)
      bfr[j] = *(const short8*)(&Ws[cur][(wc * 64 + j * 16 + n16) * 32 + ((quad * 8) ^ rkey)]);

    __builtin_amdgcn_s_setprio(1);
#pragma unroll
    for (int i = 0; i < 8; i++)
#pragma unroll
      for (int j = 0; j < 4; j++)
        acc[i][j] = __builtin_amdgcn_mfma_f32_16x16x32_bf16(af[i], bfr[j], acc[i][j], 0, 0, 0);
    __builtin_amdgcn_s_setprio(0);

    cur = (cur == 2) ? 0 : cur + 1;
  }

  float bvv[4];
#pragma unroll
  for (int j = 0; j < 4; j++) bvv[j] = Bi[bn * 256 + wc * 64 + j * 16 + n16];

  if (z == 2) {  // V^T layout [n][m]
#pragma unroll
    for (int i = 0; i < 8; i++) {
      const int rowb = bm * 256 + wr * 128 + i * 16 + quad * 4;
#pragma unroll
      for (int j = 0; j < 4; j++) {
        const int col = bn * 256 + wc * 64 + j * 16 + n16;
        short4v s;
        bf16* pb = (bf16*)&s;
#pragma unroll
        for (int r = 0; r < 4; r++) pb[r] = f2bf(acc[i][j][r] + bvv[j]);
        *(short4v*)(VTw + (size_t)col * MTOT + rowb) = s;
      }
    }
  } else {
    bf16* C = (z == 0) ? Qw : Kw;
#pragma unroll
    for (int i = 0; i < 8; i++) {
      const int rowb = bm * 256 + wr * 128 + i * 16 + quad * 4;
#pragma unroll
      for (int j = 0; j < 4; j++) {
        const int col = bn * 256 + wc * 64 + j * 16 + n16;
#pragma unroll
        for (int r = 0; r < 4; r++)
          C[(size_t)(rowb + r) * N + col] = f2bf(acc[i][j][r] + bvv[j]);
      }
    }
  }
}

// ---------------------------------------------------------------------------
// Out-proj GEMM r12: 128x64 tile. C fp32 [4096][1024] = A @ W^T + b.
// 4 waves x (32x64) = 2x4 frags, 8 MFMA + 6 ds_read per iter, async-dbuf +
// granule-swizzle. Grid 512 = 2 blocks/CU. LDS = 2*(8+4) = 24 KB.
// ---------------------------------------------------------------------------
__global__ __launch_bounds__(256) void gemm_out_kernel(
    const bf16* __restrict__ A, const bf16* __restrict__ W,
    const float* __restrict__ Bi, float* __restrict__ C) {
  constexpr int N = 1024, K = 1024;
  __shared__ bf16 As[2][128 * 32];  // 16 KB total
  __shared__ bf16 Ws[2][64 * 32];   // 8 KB total

  const int tid = threadIdx.x;
  const int w = tid >> 6, lane = tid & 63, quad = lane >> 4, n16 = lane & 15;
  const int bx = blockIdx.x;
  const int bm = bx & 31, bn = bx >> 5;  // bm-fastest (A XCD locality)
  const int wm = w * 32;

  const int rb = lane >> 2, cb = lane & 3;  // 16 rows x 4 chunks per issue
  const int gsw = (cb ^ ((rb >> 1) & 3)) * 8;  // pre-swizzled source col
  const int rkey = ((n16 >> 1) & 3) * 8;       // read-side granule XOR

  const bf16* Ag0 = A + (size_t)(bm * 128) * K;
  const bf16* Wg0 = W + (size_t)(bn * 64) * K;

  auto issue = [&](int buf, int kk) {
#pragma unroll
    for (int ii = 0; ii < 2; ii++) {
      const int R = w * 32 + ii * 16 + rb;
      async_cp16(Ag0 + (size_t)R * K + kk + gsw,
                 (void*)&As[buf][(w * 32 + ii * 16) * 32]);
    }
    const int Rw = w * 16 + rb;
    async_cp16(Wg0 + (size_t)Rw * K + kk + gsw, (void*)&Ws[buf][(w * 16) * 32]);
  };

  floatx4 acc[2][4] = {};
  issue(0, 0);
  int buf = 0;
  for (int k0 = 0; k0 < K; k0 += 32) {
    __syncthreads();
    if (k0 + 32 < K) issue(buf ^ 1, k0 + 32);

    short8 af[2], bfr[4];
#pragma unroll
    for (int i = 0; i < 2; i++)
      af[i] = *(const short8*)(&As[buf][(wm + i * 16 + n16) * 32 + ((quad * 8) ^ rkey)]);
#pragma unroll
    for (int j = 0; j < 4; j++)
      bfr[j] = *(const short8*)(&Ws[buf][(j * 16 + n16) * 32 + ((quad * 8) ^ rkey)]);
#pragma unroll
    for (int i = 0; i < 2; i++)
#pragma unroll
      for (int j = 0; j < 4; j++)
        acc[i][j] = __builtin_amdgcn_mfma_f32_16x16x32_bf16(af[i], bfr[j], acc[i][j], 0, 0, 0);
    buf ^= 1;
  }

  float bv[4];
#pragma unroll
  for (int j = 0; j < 4; j++) bv[j] = Bi[bn * 64 + j * 16 + n16];

#pragma unroll
  for (int i = 0; i < 2; i++) {
    const int rowb = bm * 128 + wm + i * 16 + quad * 4;
#pragma unroll
    for (int j = 0; j < 4; j++) {
      const int col = bn * 64 + j * 16 + n16;
#pragma unroll
      for (int r = 0; r < 4; r++)
        C[(size_t)(rowb + r) * N + col] = acc[i][j][r] + bv[j];
    }
  }
}

// ---------------------------------------------------------------------------
// Flash attention r12 (unchanged in r13): one 64-row q-tile per block,
// grid (32 hb, 32 q-tiles) = 1024 blocks; BN=64, LDS 40 KB -> 4 blocks/CU.
//  * q0 = (31 - y)*64: heaviest tiles dispatch FIRST (LPT order).
//  * XCD: linear id % 8 == hb % 8 -> q-tiles of one (h,b) share an XCD.
//  * Swapped QK^T (P store = b64x4), XOR swizzle, single-barrier dbuf,
//    setprio around PV. O aliases Q.
// ---------------------------------------------------------------------------
__global__ __launch_bounds__(256, 4) void attn_kernel(const bf16* __restrict__ Q,
                                                      const bf16* __restrict__ Kg,
                                                      const bf16* __restrict__ VT,
                                                      bf16* __restrict__ O) {
  constexpr int BN = 64;
  __shared__ bf16 Ks[2][64 * 64];  // logical (r,c) at r*64 + (c ^ ((r&7)<<3))
  __shared__ bf16 Vs[2][64 * 64];  // same swizzle; rows = d (0..63)
  __shared__ bf16 Pw[4][16 * 64];  // per-wave P strip [q=16][kv=64], same swizzle
  // total 16 + 16 + 8 = 40 KB -> 4 blocks/CU

  const int tid = threadIdx.x;
  const int w = tid >> 6, lane = tid & 63, quad = lane >> 4, n16 = lane & 15;
  const int hb = blockIdx.x;
  const int h = hb & 15, b = hb >> 4;
  const int q0 = (31 - (int)blockIdx.y) * 64;  // heaviest first (LPT)
  const size_t qoff = (size_t)b * SS * D_MODEL + h * DKH;
  const bf16* VTh = VT + (size_t)(h * DKH) * MTOT + (size_t)b * SS;

  const int kvr = tid >> 3, ck = tid & 7;  // staging: 32 rows x 8 chunks(16B)
  const int wkey = (kvr & 7) << 3;         // staging-write swizzle key
  const int swz = (n16 & 7) << 3;          // read-side / Pw swizzle key

  short8 kreg[2], vreg[2];
  auto loadKV = [&](int kv0) {
#pragma unroll
    for (int ii = 0; ii < 2; ii++) {
      kreg[ii] = *(const short8*)(Kg + qoff + (size_t)(kv0 + ii * 32 + kvr) * D_MODEL + ck * 8);
      vreg[ii] = *(const short8*)(VTh + (size_t)(ii * 32 + kvr) * MTOT + kv0 + ck * 8);
    }
  };

  bf16* pwb = &Pw[w][0];
  const int q0w = q0 + w * 16;
  const int nt = q0 / 64 + 1;  // KV tiles 0..q0/64 (diagonal last)

  short8 aQ0, aQ1;
  {
    const bf16* qp = Q + qoff + (size_t)(q0w + n16) * D_MODEL + quad * 8;
    aQ0 = *(const short8*)(qp);
    aQ1 = *(const short8*)(qp + 32);
  }

  floatx4 facc[4] = {};
  float lsum = 0.f;

  loadKV(0);
  int buf = 0;
  for (int t = 0; t < nt; t++) {
    // stage regs -> LDS buf
#pragma unroll
    for (int ii = 0; ii < 2; ii++) {
      *(short8*)(&Ks[buf][(ii * 32 + kvr) * 64 + ((ck * 8) ^ wkey)]) = kreg[ii];
      *(short8*)(&Vs[buf][(ii * 32 + kvr) * 64 + ((ck * 8) ^ wkey)]) = vreg[ii];
    }
    if (t + 1 < nt) loadKV((t + 1) * BN);  // prefetch into regs
    __syncthreads();  // single barrier per iter (dbuf)

    const int kv0 = t * BN;
    const bool lastT = (t == nt - 1);
    const bf16* ksb = &Ks[buf][0];

    // QK^T swapped: lane (quad,n16) holds P[k=kv0+blk*16+quad*4+r][q=q0w+n16]
#pragma unroll
    for (int blk = 0; blk < 4; blk++) {
      const int krow = blk * 16 + n16;
      short8 ak0 = *(const short8*)(ksb + krow * 64 + ((quad * 8) ^ swz));
      short8 ak1 = *(const short8*)(ksb + krow * 64 + ((quad * 8 + 32) ^ swz));
      floatx4 z = {};
      z = __builtin_amdgcn_mfma_f32_16x16x32_bf16(ak0, aQ0, z, 0, 0, 0);
      z = __builtin_amdgcn_mfma_f32_16x16x32_bf16(ak1, aQ1, z, 0, 0, 0);
      short4v s;
      bf16* pb = (bf16*)&s;
      if (lastT) {
        const int kbase = kv0 + blk * 16 + quad * 4, qcol = q0w + n16;
#pragma unroll
        for (int r = 0; r < 4; r++) {
          float pe = __expf(z[r] * 0.125f);
          if (kbase + r > qcol) pe = 0.f;  // causal: keep k <= q
          lsum += pe;
          pb[r] = f2bf(pe);
        }
      } else {
#pragma unroll
        for (int r = 0; r < 4; r++) {
          const float pe = __expf(z[r] * 0.125f);
          lsum += pe;
          pb[r] = f2bf(pe);
        }
      }
      // 4 consecutive k at row q=n16: one b64 write (swizzled)
      *(short4v*)(pwb + n16 * 64 + ((blk * 16 + quad * 4) ^ swz)) = s;
    }

    short8 aP[2];
#pragma unroll
    for (int c = 0; c < 2; c++)
      aP[c] = *(const short8*)(pwb + n16 * 64 + ((c * 32 + quad * 8) ^ swz));

    const bf16* vsb = &Vs[buf][0];
    __builtin_amdgcn_s_setprio(1);
#pragma unroll
    for (int d = 0; d < 4; d++)
#pragma unroll
      for (int c = 0; c < 2; c++) {
        short8 bvf = *(const short8*)(vsb + (d * 16 + n16) * 64 + ((c * 32 + quad * 8) ^ swz));
        facc[d] = __builtin_amdgcn_mfma_f32_16x16x32_bf16(aP[c], bvf, facc[d], 0, 0, 0);
      }
    __builtin_amdgcn_s_setprio(0);
    buf ^= 1;
  }

  // l[q=n16] per lane: reduce across the 4 quads, then pull per-row value
  lsum += __shfl_xor(lsum, 16);
  lsum += __shfl_xor(lsum, 32);
#pragma unroll
  for (int r = 0; r < 4; r++) {
    const float linv = 1.f / __shfl(lsum, quad * 4 + r);
    const int qrow = q0w + quad * 4 + r;
    bf16* op = O + qoff + (size_t)qrow * D_MODEL;
#pragma unroll
    for (int d = 0; d < 4; d++) op[d * 16 + n16] = f2bf(facc[d][r] * linv);
  }
}

// ---------------------------------------------------------------------------
extern "C" void kernel_launch(void* const* d_in, const int* in_sizes, int n_in,
                              void* d_out, int out_size, void* d_ws, size_t ws_size,
                              hipStream_t stream) {
  (void)in_sizes; (void)n_in; (void)out_size; (void)ws_size;
  const float* query  = (const float*)d_in[0];
  const float* key_in = (const float*)d_in[1];
  const float* value  = (const float*)d_in[2];
  // d_in[3] = mask (int32) — causal, applied analytically
  const float* w_q = (const float*)d_in[4];
  const float* b_q = (const float*)d_in[5];
  const float* w_k = (const float*)d_in[6];
  const float* b_k = (const float*)d_in[7];
  const float* w_v = (const float*)d_in[8];
  const float* b_v = (const float*)d_in[9];
  const float* w_o = (const float*)d_in[10];
  const float* b_o = (const float*)d_in[11];
  float* outp = (float*)d_out;

  const size_t mat = (size_t)MTOT * D_MODEL;  // 4M elems
  bf16* Qws  = (bf16*)d_ws;   // 8 MB; attention O aliases this
  bf16* Kws  = Qws + mat;     // 8 MB
  bf16* VTws = Kws + mat;     // 8 MB (V transposed, per-head rows)
  bf16* Wb   = VTws + mat;    // 8 MB: wq|wk|wv|wo bf16
  bf16* Vi   = Wb + 4 * (size_t)(1 << 20);  // 8 MB: converted value input
  // Converted q/k inputs live in d_out (16 MB) — consumed by gemm_qkv before
  // gemm_out overwrites d_out (stream-ordered).
  bf16* Qi = (bf16*)d_out;
  bf16* Ki = Qi + mat;

  convert_kernel<<<16384, 256, 0, stream>>>(w_q, w_k, w_v, w_o, query, key_in,
                                            value, Wb, Qi, Ki, Vi);

  dim3 gq(64, 1, 3);  // x = bm + 16*bn (bm-fastest), 256x256 tiles
  gemm_qkv_kernel<<<gq, 512, 0, stream>>>(Qi, Ki, Vi, Wb, b_q, b_k, b_v, Qws,
                                          Kws, VTws);
  dim3 ga(NH * BB, 32);  // x = head-batch (fastest), y: q0 = (31-y)*64
  attn_kernel<<<ga, 256, 0, stream>>>(Qws, Kws, VTws, Qws);
  gemm_out_kernel<<<512, 256, 0, stream>>>(Qws, Wb + ((size_t)3 << 20), b_o, outp);
}

// Round 5
// 223.446 us; speedup vs baseline: 1.0723x; 1.0723x over previous
//
#include <hip/hip_runtime.h>
#include <hip/hip_bf16.h>

#define D_MODEL 1024
#define NH 16
#define DKH 64
#define BB 2
#define SS 2048
#define MTOT (BB * SS)  // 4096

typedef __hip_bfloat16 bf16;
typedef __attribute__((ext_vector_type(8))) short short8;
typedef __attribute__((ext_vector_type(4))) short short4v;
typedef __attribute__((ext_vector_type(4))) float floatx4;

__device__ __forceinline__ bf16 f2bf(float x) { return __float2bfloat16(x); }

// async global->LDS, 16B per lane; LDS dest must be wave-uniform (HW adds lane*16)
__device__ __forceinline__ void async_cp16(const void* g, void* l) {
  __builtin_amdgcn_global_load_lds(
      (const __attribute__((address_space(1))) unsigned int*)g,
      (__attribute__((address_space(3))) unsigned int*)l, 16, 0, 0);
}

// ---------------------------------------------------------------------------
// Pre-conversion fp32 -> bf16: 4 weight matrices (4 x 1M elems) AND the three
// input activations (3 x 4M elems). Removes all fp32 handling from the GEMMs.
// Converted q/k live in d_out (16 MB, not written until out-proj,
// stream-ordered); v lives in ws.
// ---------------------------------------------------------------------------
__global__ __launch_bounds__(256) void convert_kernel(
    const float* __restrict__ wq, const float* __restrict__ wk,
    const float* __restrict__ wv, const float* __restrict__ wo,
    const float* __restrict__ qi, const float* __restrict__ ki,
    const float* __restrict__ vi, bf16* __restrict__ Wb,
    bf16* __restrict__ Qi, bf16* __restrict__ Ki, bf16* __restrict__ Vi) {
  const int id = blockIdx.x * 256 + threadIdx.x;  // float4 index, 0..4M-1
  const float* src;
  bf16* dst;
  if (id < (1 << 20)) {  // weights: 4 x 256K float4
    const int m = id >> 18, loc = id & 0x3FFFF;
    src = ((m == 0) ? wq : (m == 1) ? wk : (m == 2) ? wv : wo) + (size_t)loc * 4;
    dst = Wb + ((size_t)m << 20) + (size_t)loc * 4;
  } else {  // inputs: 3 x 1M float4
    const int t = id - (1 << 20);
    const int m = t >> 20, loc = t & 0xFFFFF;
    src = ((m == 0) ? qi : (m == 1) ? ki : vi) + (size_t)loc * 4;
    dst = ((m == 0) ? Qi : (m == 1) ? Ki : Vi) + (size_t)loc * 4;
  }
  const float4 v = *(const float4*)src;
  short4v s;
  bf16* pb = (bf16*)&s;
  pb[0] = f2bf(v.x); pb[1] = f2bf(v.y); pb[2] = f2bf(v.z); pb[3] = f2bf(v.w);
  *(short4v*)dst = s;
}

// ---------------------------------------------------------------------------
// QKV GEMM r14: r11/r12 geometry (128x128 tile, BK=32, 4 waves, grid 768 =
// 3 blocks/CU, 12 waves/CU) + the r13-proven counted-vmcnt sync: 3 LDS
// buffers (48 KB), per iter s_waitcnt vmcnt(4) (drains ONLY the current
// buffer's 4 global_load_lds; next tile's 4 stay in flight) + raw s_barrier
// (no compiler vmcnt(0) drain). r13's regression was occupancy (1 block/CU,
// grid 192), not the sync — this keeps r12's residency.
// Ledger: 4 cp16/thread/tile; prologue 8 outstanding; steady drain4/issue4;
// vmcnt(0) only at t=31. Buffer-reuse: writes into (t+2)%3 occur after
// barrier t; that buf's last readers (iter t-1) finished LDS reads (lgkm
// inserted by compiler before MFMA use) before reaching barrier t.
// r11 granule swizzle carried (proven 0-conflict).
// mode: 0 = bf16 row-major C; 1 = bf16 V^T layout [n][m].
// ---------------------------------------------------------------------------
__device__ __forceinline__ void gemm_qkv_body(const bf16* __restrict__ A,
                                              const bf16* __restrict__ W,
                                              const float* __restrict__ Bi,
                                              bf16* __restrict__ C, int mode) {
  constexpr int N = 1024, K = 1024, NT = K / 32;
  __shared__ bf16 As[3][128 * 32];  // 24 KB
  __shared__ bf16 Ws[3][128 * 32];  // 24 KB

  const int tid = threadIdx.x;
  const int w = tid >> 6, lane = tid & 63, quad = lane >> 4, n16 = lane & 15;
  const int bx = blockIdx.x;
  const int bm = bx & 31, bn = bx >> 5;  // bm-fastest (XCD locality for A)
  const int wm = (w & 1) * 64, wn = (w >> 1) * 64;

  const int rb = lane >> 2, cb = lane & 3;  // 16 rows x 4 chunks(16B) per issue
  const int gsw = (cb ^ ((rb >> 1) & 3)) * 8;  // pre-swizzled source col (elems)
  const int rkey = ((n16 >> 1) & 3) * 8;       // read-side granule XOR (elems)

  const bf16* Ag0 = A + (size_t)(bm * 128) * K;
  const bf16* Wg0 = W + (size_t)(bn * 128) * K;

  auto issue = [&](int buf, int k0) {
#pragma unroll
    for (int ii = 0; ii < 2; ii++) {
      const int R = w * 32 + ii * 16 + rb;
      async_cp16(Ag0 + (size_t)R * K + k0 + gsw,
                 (void*)&As[buf][(w * 32 + ii * 16) * 32]);
      async_cp16(Wg0 + (size_t)R * K + k0 + gsw,
                 (void*)&Ws[buf][(w * 32 + ii * 16) * 32]);
    }
  };

  floatx4 acc[4][4] = {};
  issue(0, 0);
  issue(1, 32);
  int cur = 0;
  for (int t = 0; t < NT; t++) {
    if (t < NT - 1) {
      asm volatile("s_waitcnt vmcnt(4)" ::: "memory");  // drain cur buf only
    } else {
      asm volatile("s_waitcnt vmcnt(0)" ::: "memory");  // final drain
    }
    __builtin_amdgcn_s_barrier();       // raw: no implicit vmcnt(0)
    __builtin_amdgcn_sched_barrier(0);  // pin reads below the barrier

    if (t < NT - 2) {  // prefetch 2 tiles ahead into the buf being freed
      int nb = cur + 2;
      if (nb >= 3) nb -= 3;
      issue(nb, (t + 2) * 32);
    }

    short8 af[4], bfr[4];
#pragma unroll
    for (int i = 0; i < 4; i++)
      af[i] = *(const short8*)(&As[cur][(wm + i * 16 + n16) * 32 + ((quad * 8) ^ rkey)]);
#pragma unroll
    for (int j = 0; j < 4; j++)
      bfr[j] = *(const short8*)(&Ws[cur][(wn + j * 16 + n16) * 32 + ((quad * 8) ^ rkey)]);
#pragma unroll
    for (int i = 0; i < 4; i++)
#pragma unroll
      for (int j = 0; j < 4; j++)
        acc[i][j] = __builtin_amdgcn_mfma_f32_16x16x32_bf16(af[i], bfr[j], acc[i][j], 0, 0, 0);

    cur = (cur == 2) ? 0 : cur + 1;
  }

  float bv[4];
#pragma unroll
  for (int j = 0; j < 4; j++) bv[j] = Bi[bn * 128 + wn + j * 16 + n16];

#pragma unroll
  for (int i = 0; i < 4; i++) {
    const int rowb = bm * 128 + wm + i * 16 + quad * 4;
#pragma unroll
    for (int j = 0; j < 4; j++) {
      const int col = bn * 128 + wn + j * 16 + n16;
      if (mode == 1) {
        short4v s;
        bf16* pb = (bf16*)&s;
#pragma unroll
        for (int r = 0; r < 4; r++) pb[r] = f2bf(acc[i][j][r] + bv[j]);
        *(short4v*)(C + (size_t)col * MTOT + rowb) = s;
      } else {
#pragma unroll
        for (int r = 0; r < 4; r++)
          C[(size_t)(rowb + r) * N + col] = f2bf(acc[i][j][r] + bv[j]);
      }
    }
  }
}

__global__ __launch_bounds__(256) void gemm_qkv_kernel(
    const bf16* __restrict__ Qi, const bf16* __restrict__ Ki,
    const bf16* __restrict__ Vi, const bf16* __restrict__ Wb,
    const float* __restrict__ bq, const float* __restrict__ bk,
    const float* __restrict__ bv, bf16* __restrict__ Qw,
    bf16* __restrict__ Kw, bf16* __restrict__ VTw) {
  const int z = blockIdx.z;
  const bf16* A = (z == 0) ? Qi : (z == 1) ? Ki : Vi;
  const bf16* W = Wb + ((size_t)z << 20);
  const float* Bi = (z == 0) ? bq : (z == 1) ? bk : bv;
  bf16* C = (z == 0) ? Qw : (z == 1) ? Kw : VTw;
  gemm_qkv_body(A, W, Bi, C, (z == 2) ? 1 : 0);
}

// ---------------------------------------------------------------------------
// Out-proj GEMM r14: r12 geometry (128x64 tile, 4 waves x 2x4 frags, grid
// 512 = 2 blocks/CU) + 3-buffer counted vmcnt (36 KB LDS). 3 cp16/thread/
// tile -> steady vmcnt(3); vmcnt(0) only at final iter.
// ---------------------------------------------------------------------------
__global__ __launch_bounds__(256) void gemm_out_kernel(
    const bf16* __restrict__ A, const bf16* __restrict__ W,
    const float* __restrict__ Bi, float* __restrict__ C) {
  constexpr int N = 1024, K = 1024, NT = K / 32;
  __shared__ bf16 As[3][128 * 32];  // 24 KB
  __shared__ bf16 Ws[3][64 * 32];   // 12 KB

  const int tid = threadIdx.x;
  const int w = tid >> 6, lane = tid & 63, quad = lane >> 4, n16 = lane & 15;
  const int bx = blockIdx.x;
  const int bm = bx & 31, bn = bx >> 5;  // bm-fastest (A XCD locality)
  const int wm = w * 32;

  const int rb = lane >> 2, cb = lane & 3;  // 16 rows x 4 chunks per issue
  const int gsw = (cb ^ ((rb >> 1) & 3)) * 8;  // pre-swizzled source col
  const int rkey = ((n16 >> 1) & 3) * 8;       // read-side granule XOR

  const bf16* Ag0 = A + (size_t)(bm * 128) * K;
  const bf16* Wg0 = W + (size_t)(bn * 64) * K;

  auto issue = [&](int buf, int kk) {
#pragma unroll
    for (int ii = 0; ii < 2; ii++) {
      const int R = w * 32 + ii * 16 + rb;
      async_cp16(Ag0 + (size_t)R * K + kk + gsw,
                 (void*)&As[buf][(w * 32 + ii * 16) * 32]);
    }
    const int Rw = w * 16 + rb;
    async_cp16(Wg0 + (size_t)Rw * K + kk + gsw, (void*)&Ws[buf][(w * 16) * 32]);
  };

  floatx4 acc[2][4] = {};
  issue(0, 0);
  issue(1, 32);
  int cur = 0;
  for (int t = 0; t < NT; t++) {
    if (t < NT - 1) {
      asm volatile("s_waitcnt vmcnt(3)" ::: "memory");
    } else {
      asm volatile("s_waitcnt vmcnt(0)" ::: "memory");
    }
    __builtin_amdgcn_s_barrier();
    __builtin_amdgcn_sched_barrier(0);

    if (t < NT - 2) {
      int nb = cur + 2;
      if (nb >= 3) nb -= 3;
      issue(nb, (t + 2) * 32);
    }

    short8 af[2], bfr[4];
#pragma unroll
    for (int i = 0; i < 2; i++)
      af[i] = *(const short8*)(&As[cur][(wm + i * 16 + n16) * 32 + ((quad * 8) ^ rkey)]);
#pragma unroll
    for (int j = 0; j < 4; j++)
      bfr[j] = *(const short8*)(&Ws[cur][(j * 16 + n16) * 32 + ((quad * 8) ^ rkey)]);
#pragma unroll
    for (int i = 0; i < 2; i++)
#pragma unroll
      for (int j = 0; j < 4; j++)
        acc[i][j] = __builtin_amdgcn_mfma_f32_16x16x32_bf16(af[i], bfr[j], acc[i][j], 0, 0, 0);

    cur = (cur == 2) ? 0 : cur + 1;
  }

  float bv[4];
#pragma unroll
  for (int j = 0; j < 4; j++) bv[j] = Bi[bn * 64 + j * 16 + n16];

#pragma unroll
  for (int i = 0; i < 2; i++) {
    const int rowb = bm * 128 + wm + i * 16 + quad * 4;
#pragma unroll
    for (int j = 0; j < 4; j++) {
      const int col = bn * 64 + j * 16 + n16;
#pragma unroll
      for (int r = 0; r < 4; r++)
        C[(size_t)(rowb + r) * N + col] = acc[i][j][r] + bv[j];
    }
  }
}

// ---------------------------------------------------------------------------
// Flash attention r14: r12 structure, but the per-iter __syncthreads is
// replaced by {s_waitcnt lgkmcnt(0); s_barrier; sched_barrier(0)}.
// __syncthreads emits vmcnt(0) right after loadKV(t+1) issues its register
// prefetch — draining it on the spot and exposing full HBM latency every KV
// iteration. lgkmcnt(0)+barrier keeps identical LDS safety (all this wave's
// ds reads/writes complete before the barrier) while the global prefetch
// stays in flight; the register-dependency vmcnt wait lands at next iter's
// ds_write, after a full compute phase of cover.
// Geometry (r12): one 64-row q-tile per block, grid (32 hb, 32 q) = 1024
// blocks, BN=64, LDS 40 KB -> 4 blocks/CU. LPT order (q0 = (31-y)*64),
// XCD-local hb, swapped QK^T, XOR swizzle, setprio around PV. O aliases Q.
// ---------------------------------------------------------------------------
__global__ __launch_bounds__(256, 4) void attn_kernel(const bf16* __restrict__ Q,
                                                      const bf16* __restrict__ Kg,
                                                      const bf16* __restrict__ VT,
                                                      bf16* __restrict__ O) {
  constexpr int BN = 64;
  __shared__ bf16 Ks[2][64 * 64];  // logical (r,c) at r*64 + (c ^ ((r&7)<<3))
  __shared__ bf16 Vs[2][64 * 64];  // same swizzle; rows = d (0..63)
  __shared__ bf16 Pw[4][16 * 64];  // per-wave P strip [q=16][kv=64], same swizzle
  // total 16 + 16 + 8 = 40 KB -> 4 blocks/CU

  const int tid = threadIdx.x;
  const int w = tid >> 6, lane = tid & 63, quad = lane >> 4, n16 = lane & 15;
  const int hb = blockIdx.x;
  const int h = hb & 15, b = hb >> 4;
  const int q0 = (31 - (int)blockIdx.y) * 64;  // heaviest first (LPT)
  const size_t qoff = (size_t)b * SS * D_MODEL + h * DKH;
  const bf16* VTh = VT + (size_t)(h * DKH) * MTOT + (size_t)b * SS;

  const int kvr = tid >> 3, ck = tid & 7;  // staging: 32 rows x 8 chunks(16B)
  const int wkey = (kvr & 7) << 3;         // staging-write swizzle key
  const int swz = (n16 & 7) << 3;          // read-side / Pw swizzle key

  short8 kreg[2], vreg[2];
  auto loadKV = [&](int kv0) {
#pragma unroll
    for (int ii = 0; ii < 2; ii++) {
      kreg[ii] = *(const short8*)(Kg + qoff + (size_t)(kv0 + ii * 32 + kvr) * D_MODEL + ck * 8);
      vreg[ii] = *(const short8*)(VTh + (size_t)(ii * 32 + kvr) * MTOT + kv0 + ck * 8);
    }
  };

  bf16* pwb = &Pw[w][0];
  const int q0w = q0 + w * 16;
  const int nt = q0 / 64 + 1;  // KV tiles 0..q0/64 (diagonal last)

  short8 aQ0, aQ1;
  {
    const bf16* qp = Q + qoff + (size_t)(q0w + n16) * D_MODEL + quad * 8;
    aQ0 = *(const short8*)(qp);
    aQ1 = *(const short8*)(qp + 32);
  }

  floatx4 facc[4] = {};
  float lsum = 0.f;

  loadKV(0);
  int buf = 0;
  for (int t = 0; t < nt; t++) {
    // stage regs -> LDS buf (vmcnt waits inserted by compiler via reg deps)
#pragma unroll
    for (int ii = 0; ii < 2; ii++) {
      *(short8*)(&Ks[buf][(ii * 32 + kvr) * 64 + ((ck * 8) ^ wkey)]) = kreg[ii];
      *(short8*)(&Vs[buf][(ii * 32 + kvr) * 64 + ((ck * 8) ^ wkey)]) = vreg[ii];
    }
    if (t + 1 < nt) loadKV((t + 1) * BN);  // prefetch into regs
    // __syncthreads minus the vmcnt(0) drain: prefetch stays in flight
    asm volatile("s_waitcnt lgkmcnt(0)" ::: "memory");
    __builtin_amdgcn_s_barrier();
    __builtin_amdgcn_sched_barrier(0);

    const int kv0 = t * BN;
    const bool lastT = (t == nt - 1);
    const bf16* ksb = &Ks[buf][0];

    // QK^T swapped: lane (quad,n16) holds P[k=kv0+blk*16+quad*4+r][q=q0w+n16]
#pragma unroll
    for (int blk = 0; blk < 4; blk++) {
      const int krow = blk * 16 + n16;
      short8 ak0 = *(const short8*)(ksb + krow * 64 + ((quad * 8) ^ swz));
      short8 ak1 = *(const short8*)(ksb + krow * 64 + ((quad * 8 + 32) ^ swz));
      floatx4 z = {};
      z = __builtin_amdgcn_mfma_f32_16x16x32_bf16(ak0, aQ0, z, 0, 0, 0);
      z = __builtin_amdgcn_mfma_f32_16x16x32_bf16(ak1, aQ1, z, 0, 0, 0);
      short4v s;
      bf16* pb = (bf16*)&s;
      if (lastT) {
        const int kbase = kv0 + blk * 16 + quad * 4, qcol = q0w + n16;
#pragma unroll
        for (int r = 0; r < 4; r++) {
          float pe = __expf(z[r] * 0.125f);
          if (kbase + r > qcol) pe = 0.f;  // causal: keep k <= q
          lsum += pe;
          pb[r] = f2bf(pe);
        }
      } else {
#pragma unroll
        for (int r = 0; r < 4; r++) {
          const float pe = __expf(z[r] * 0.125f);
          lsum += pe;
          pb[r] = f2bf(pe);
        }
      }
      // 4 consecutive k at row q=n16: one b64 write (swizzled)
      *(short4v*)(pwb + n16 * 64 + ((blk * 16 + quad * 4) ^ swz)) = s;
    }

    short8 aP[2];
#pragma unroll
    for (int c = 0; c < 2; c++)
      aP[c] = *(const short8*)(pwb + n16 * 64 + ((c * 32 + quad * 8) ^ swz));

    const bf16* vsb = &Vs[buf][0];
    __builtin_amdgcn_s_setprio(1);
#pragma unroll
    for (int d = 0; d < 4; d++)
#pragma unroll
      for (int c = 0; c < 2; c++) {
        short8 bvf = *(const short8*)(vsb + (d * 16 + n16) * 64 + ((c * 32 + quad * 8) ^ swz));
        facc[d] = __builtin_amdgcn_mfma_f32_16x16x32_bf16(aP[c], bvf, facc[d], 0, 0, 0);
      }
    __builtin_amdgcn_s_setprio(0);
    buf ^= 1;
  }

  // l[q=n16] per lane: reduce across the 4 quads, then pull per-row value
  lsum += __shfl_xor(lsum, 16);
  lsum += __shfl_xor(lsum, 32);
#pragma unroll
  for (int r = 0; r < 4; r++) {
    const float linv = 1.f / __shfl(lsum, quad * 4 + r);
    const int qrow = q0w + quad * 4 + r;
    bf16* op = O + qoff + (size_t)qrow * D_MODEL;
#pragma unroll
    for (int d = 0; d < 4; d++) op[d * 16 + n16] = f2bf(facc[d][r] * linv);
  }
}

// ---------------------------------------------------------------------------
extern "C" void kernel_launch(void* const* d_in, const int* in_sizes, int n_in,
                              void* d_out, int out_size, void* d_ws, size_t ws_size,
                              hipStream_t stream) {
  (void)in_sizes; (void)n_in; (void)out_size; (void)ws_size;
  const float* query  = (const float*)d_in[0];
  const float* key_in = (const float*)d_in[1];
  const float* value  = (const float*)d_in[2];
  // d_in[3] = mask (int32) — causal, applied analytically
  const float* w_q = (const float*)d_in[4];
  const float* b_q = (const float*)d_in[5];
  const float* w_k = (const float*)d_in[6];
  const float* b_k = (const float*)d_in[7];
  const float* w_v = (const float*)d_in[8];
  const float* b_v = (const float*)d_in[9];
  const float* w_o = (const float*)d_in[10];
  const float* b_o = (const float*)d_in[11];
  float* outp = (float*)d_out;

  const size_t mat = (size_t)MTOT * D_MODEL;  // 4M elems
  bf16* Qws  = (bf16*)d_ws;   // 8 MB; attention O aliases this
  bf16* Kws  = Qws + mat;     // 8 MB
  bf16* VTws = Kws + mat;     // 8 MB (V transposed, per-head rows)
  bf16* Wb   = VTws + mat;    // 8 MB: wq|wk|wv|wo bf16
  bf16* Vi   = Wb + 4 * (size_t)(1 << 20);  // 8 MB: converted value input
  // Converted q/k inputs live in d_out (16 MB) — consumed by gemm_qkv before
  // gemm_out overwrites d_out (stream-ordered).
  bf16* Qi = (bf16*)d_out;
  bf16* Ki = Qi + mat;

  convert_kernel<<<16384, 256, 0, stream>>>(w_q, w_k, w_v, w_o, query, key_in,
                                            value, Wb, Qi, Ki, Vi);

  dim3 gq(256, 1, 3);  // x = bm + 32*bn (bm-fastest), 128x128 tiles
  gemm_qkv_kernel<<<gq, 256, 0, stream>>>(Qi, Ki, Vi, Wb, b_q, b_k, b_v, Qws,
                                          Kws, VTws);
  dim3 ga(NH * BB, 32);  // x = head-batch (fastest), y: q0 = (31-y)*64
  attn_kernel<<<ga, 256, 0, stream>>>(Qws, Kws, VTws, Qws);
  gemm_out_kernel<<<512, 256, 0, stream>>>(Qws, Wb + ((size_t)3 << 20), b_o, outp);
}